// Round 1
// baseline (678.825 us; speedup 1.0000x reference)
//
#include <hip/hip_runtime.h>
#include <hip/hip_bf16.h>

// Problem: out[i,m] = sum_{j,k,l} G[j,k] * x[i,k,l] * (v-w)[j,l,m]
// i(BATCH)=256, j(NEURONS)=1024, k(N_FEAT)=1024, l(IN_DIM)=256, m(OUT_DIM)=128
//
// Factorization (86 GFLOP total, minimal):
//   T[k,l,m] = sum_j G[j,k] * (v-w)[j,l,m]        (GEMM 1024 x 32768 x K=1024)
//   out[i,m] = sum_{k,l} x[i,k,l] * T[k,l,m]      (GEMM 256 x 128 x K=262144, split-K)
//
// Layouts (all GEMM operands K-contiguous for global_load_lds + ds_read_b128):
//   Gt[k*1024 + j]                      bf16, A of stage 1
//   Dt[(m*256+l)*1024 + j]              bf16, B of stage 1 (n' = m*256+l)
//   Tt[m*262144 + k*256 + l]            bf16, stage-1 out = B^T of stage 2 (m-major, kl=k*256+l)
//   x natural [i][k*256+l] fp32 -> cvt bf16 in-register (A of stage 2)

typedef __attribute__((ext_vector_type(8))) short bf16x8;
typedef __attribute__((ext_vector_type(4))) float f32x4;

#define AS1C(p) ((const __attribute__((address_space(1))) void*)(p))
#define AS3(p)  ((__attribute__((address_space(3))) void*)(p))

__device__ __forceinline__ unsigned short f2bf(float f) {
    unsigned u = __float_as_uint(f);
    unsigned r = u + 0x7fffu + ((u >> 16) & 1u);   // round-to-nearest-even
    return (unsigned short)(r >> 16);
}

// ---------------- prep: Gt[k][j] = bf16(G[j][k]) ----------------
// grid (32,32), block (32,8)
__global__ void prep_G(const float* __restrict__ G, unsigned short* __restrict__ Gt) {
    __shared__ float tile[32][33];
    int k0 = blockIdx.x * 32, j0 = blockIdx.y * 32;
    int tx = threadIdx.x, ty = threadIdx.y;
    #pragma unroll
    for (int r = 0; r < 32; r += 8)
        tile[ty + r][tx] = G[(size_t)(j0 + ty + r) * 1024 + k0 + tx];   // tile[jloc][kloc]
    __syncthreads();
    #pragma unroll
    for (int r = 0; r < 32; r += 8)
        Gt[(size_t)(k0 + ty + r) * 1024 + j0 + tx] = f2bf(tile[tx][ty + r]);
}

// ---------------- prep: Dt[(m*256+l)*1024 + j] = bf16(v-w) ----------------
// grid (32, 256): bx = j-tile (32 wide), by = l.  block 256.
__global__ void prep_D(const float* __restrict__ v, const float* __restrict__ w,
                       unsigned short* __restrict__ Dt) {
    __shared__ unsigned short tile[32][132];   // [j][m], padded
    int j0 = blockIdx.x * 32;
    int l  = blockIdx.y;
    int t  = threadIdx.x;
    // read 32(j) x 128(m) fp32 of v,w at this l (coalesced along m)
    #pragma unroll
    for (int it = 0; it < 16; ++it) {
        int idx = it * 256 + t;
        int j = idx >> 7, m = idx & 127;
        size_t g = (size_t)(j0 + j) * 32768 + (size_t)l * 128 + m;
        tile[j][m] = f2bf(v[g] - w[g]);
    }
    __syncthreads();
    // write: 128 rows n'=(m*256+l), each a 32-half j-run; 2 threads/row x 16 halfs
    int m = t >> 1, half = t & 1;
    unsigned short vals[16];
    #pragma unroll
    for (int q = 0; q < 16; ++q) vals[q] = tile[half * 16 + q][m];
    size_t dst = ((size_t)m * 256 + l) * 1024 + j0 + half * 16;
    *(uint4*)(Dt + dst)     = *(uint4*)(vals);
    *(uint4*)(Dt + dst + 8) = *(uint4*)(vals + 8);
}

// ---------------- stage 1: Tt = Gt (1024x1024) @ Dt^T (1024x32768) ----------------
// M=1024(k) N=32768(n'=m*256+l) K=1024(j).  128x128 tile, BK=32, 4 waves, 4x4 MFMA/wave.
// grid (8, 256), block 256.
__global__ __launch_bounds__(256) void gemm1(const unsigned short* __restrict__ Gt,
                                             const unsigned short* __restrict__ Dt,
                                             unsigned short* __restrict__ Tt) {
    __shared__ __align__(16) unsigned short As[128 * 32];
    __shared__ __align__(16) unsigned short Bs[128 * 32];
    int tid = threadIdx.x, wv = tid >> 6, lane = tid & 63;
    int k0 = blockIdx.x * 128, n0 = blockIdx.y * 128;
    int ldrow = lane >> 2, ldcol = (lane & 3) * 8;
    int wr = (wv >> 1) * 64, wc = (wv & 1) * 64;
    int quad = lane >> 4, l15 = lane & 15;

    f32x4 acc[4][4] = {};

    for (int j0 = 0; j0 < 1024; j0 += 32) {
        #pragma unroll
        for (int i = 0; i < 2; ++i) {
            int r = wv * 32 + i * 16;   // wave-uniform LDS dest; lane scatters +lane*16B
            __builtin_amdgcn_global_load_lds(
                AS1C(Gt + (size_t)(k0 + r + ldrow) * 1024 + j0 + ldcol),
                AS3(As + r * 32), 16, 0, 0);
            __builtin_amdgcn_global_load_lds(
                AS1C(Dt + (size_t)(n0 + r + ldrow) * 1024 + j0 + ldcol),
                AS3(Bs + r * 32), 16, 0, 0);
        }
        __syncthreads();
        bf16x8 a[4], b[4];
        #pragma unroll
        for (int rt = 0; rt < 4; ++rt)
            a[rt] = *(const bf16x8*)(As + (wr + rt * 16 + l15) * 32 + quad * 8);
        #pragma unroll
        for (int ct = 0; ct < 4; ++ct)
            b[ct] = *(const bf16x8*)(Bs + (wc + ct * 16 + l15) * 32 + quad * 8);
        #pragma unroll
        for (int rt = 0; rt < 4; ++rt)
            #pragma unroll
            for (int ct = 0; ct < 4; ++ct)
                acc[rt][ct] = __builtin_amdgcn_mfma_f32_16x16x32_bf16(a[rt], b[ct], acc[rt][ct], 0, 0, 0);
        __syncthreads();
    }
    // epilogue: C[k][n'] -> Tt[m*262144 + k*256 + l], n' = m*256+l
    #pragma unroll
    for (int rt = 0; rt < 4; ++rt)
        #pragma unroll
        for (int ct = 0; ct < 4; ++ct) {
            int col = wc + ct * 16 + l15;
            int np  = n0 + col;
            int mm  = np >> 8, ll = np & 255;
            #pragma unroll
            for (int r = 0; r < 4; ++r) {
                int k = k0 + wr + rt * 16 + quad * 4 + r;
                Tt[(size_t)mm * 262144 + (size_t)k * 256 + ll] = f2bf(acc[rt][ct][r]);
            }
        }
}

// ---------------- stage 2: out(256x128) = x(256x262144) @ Tt^T, split-K ----------------
// grid (4, 128): 64-row i-tile x 2048-wide K-chunk. block 256. atomicAdd fp32.
__global__ __launch_bounds__(256) void gemm2(const float* __restrict__ x,
                                             const unsigned short* __restrict__ Tt,
                                             float* __restrict__ out) {
    __shared__ __align__(16) unsigned short Xs[64 * 32];
    __shared__ __align__(16) unsigned short Ts[128 * 32];
    int tid = threadIdx.x, wv = tid >> 6, lane = tid & 63;
    int i0 = blockIdx.x * 64;
    size_t kl0 = (size_t)blockIdx.y * 2048;
    int ldrow = lane >> 2, ldcol = (lane & 3) * 8;
    int wr = (wv >> 1) * 32, wc = (wv & 1) * 64;
    int quad = lane >> 4, l15 = lane & 15;

    f32x4 acc[2][4] = {};

    for (int it = 0; it < 64; ++it) {
        size_t kk = kl0 + it * 32;
        #pragma unroll
        for (int i = 0; i < 2; ++i) {
            int r = wv * 32 + i * 16;
            __builtin_amdgcn_global_load_lds(
                AS1C(Tt + (size_t)(r + ldrow) * 262144 + kk + ldcol),
                AS3(Ts + r * 32), 16, 0, 0);
        }
        // x: 64 rows x 32 cols fp32 -> bf16; 512 float4s, 2 per thread
        #pragma unroll
        for (int i = 0; i < 2; ++i) {
            int f = tid + i * 256;
            int r = f >> 3, c = (f & 7) * 4;
            float4 xv = *(const float4*)(x + (size_t)(i0 + r) * 262144 + kk + c);
            unsigned short h[4] = {f2bf(xv.x), f2bf(xv.y), f2bf(xv.z), f2bf(xv.w)};
            *(uint2*)(Xs + r * 32 + c) = *(uint2*)h;
        }
        __syncthreads();
        bf16x8 a[2], b[4];
        #pragma unroll
        for (int rt = 0; rt < 2; ++rt)
            a[rt] = *(const bf16x8*)(Xs + (wr + rt * 16 + l15) * 32 + quad * 8);
        #pragma unroll
        for (int ct = 0; ct < 4; ++ct)
            b[ct] = *(const bf16x8*)(Ts + (wc + ct * 16 + l15) * 32 + quad * 8);
        #pragma unroll
        for (int rt = 0; rt < 2; ++rt)
            #pragma unroll
            for (int ct = 0; ct < 4; ++ct)
                acc[rt][ct] = __builtin_amdgcn_mfma_f32_16x16x32_bf16(a[rt], b[ct], acc[rt][ct], 0, 0, 0);
        __syncthreads();
    }
    #pragma unroll
    for (int rt = 0; rt < 2; ++rt)
        #pragma unroll
        for (int ct = 0; ct < 4; ++ct)
            #pragma unroll
            for (int r = 0; r < 4; ++r) {
                int i  = i0 + wr + rt * 16 + quad * 4 + r;
                int mo = wc + ct * 16 + l15;
                atomicAdd(&out[(size_t)i * 128 + mo], acc[rt][ct][r]);
            }
}

extern "C" void kernel_launch(void* const* d_in, const int* in_sizes, int n_in,
                              void* d_out, int out_size, void* d_ws, size_t ws_size,
                              hipStream_t stream) {
    const float* x = (const float*)d_in[0];   // 256*1024*256
    const float* G = (const float*)d_in[1];   // 1024*1024
    const float* v = (const float*)d_in[2];   // 1024*256*128
    const float* w = (const float*)d_in[3];   // 1024*256*128
    float* out = (float*)d_out;               // 256*128 fp32

    char* ws = (char*)d_ws;
    unsigned short* Dt = (unsigned short*)(ws);                  // 67,108,864 B
    unsigned short* Tt = (unsigned short*)(ws + 67108864);       // 67,108,864 B
    unsigned short* Gt = (unsigned short*)(ws + 134217728);      //  2,097,152 B

    hipMemsetAsync(d_out, 0, (size_t)256 * 128 * sizeof(float), stream);
    prep_G<<<dim3(32, 32), dim3(32, 8), 0, stream>>>(G, Gt);
    prep_D<<<dim3(32, 256), 256, 0, stream>>>(v, w, Dt);
    gemm1<<<dim3(8, 256), 256, 0, stream>>>(Gt, Dt, Tt);
    gemm2<<<dim3(4, 128), 256, 0, stream>>>(x, Tt, out);
}